// Round 12
// baseline (327.184 us; speedup 1.0000x reference)
//
#include <hip/hip_runtime.h>
#include <math.h>

constexpr int Bn = 4, Cc = 128, On = 128, Hh = 160, Ww = 160, Kk = 9;
constexpr int HW = Hh * Ww;          // 25600
constexpr int OMP = 69;              // om_lds row pitch (floats), bank-spread

typedef __attribute__((ext_vector_type(8))) short s16x8;
typedef __attribute__((ext_vector_type(4))) float f32x4;

__device__ inline float bf2f(short s) {
    union { float f; unsigned u; } v;
    v.u = ((unsigned)(unsigned short)s) << 16;
    return v.f;
}
__device__ inline short f2bf(float f) {
    union { float f; unsigned u; } v;
    v.f = f;
    unsigned r = v.u + 0x7fffu + ((v.u >> 16) & 1u);   // RNE
    return (short)(r >> 16);
}

// ---------------------------------------------------------------------------
// Kernel A1: x (NCHW f32) -> xT (NHWC bf16 hi) + xLo (NHWC bf16 lo).
// ---------------------------------------------------------------------------
__global__ __launch_bounds__(256) void to_nhwc(const float* __restrict__ x,
                                               short* __restrict__ xT,
                                               short* __restrict__ xLo) {
    __shared__ float tile[128][65];
    const int t = threadIdx.x;
    const int p0 = blockIdx.x * 64;
    const int b = blockIdx.y;
#pragma unroll
    for (int i = 0; i < 32; ++i) {
        int c = i * 4 + (t >> 6);
        tile[c][t & 63] = x[((size_t)b * Cc + c) * HW + p0 + (t & 63)];
    }
    __syncthreads();
    const int px = t >> 2, cq = t & 3;
    short* dsth = xT  + ((size_t)(b * HW) + p0 + px) * Cc;
    short* dstl = xLo + ((size_t)(b * HW) + p0 + px) * Cc;
#pragma unroll
    for (int j = 0; j < 8; ++j) {
        int c0 = cq * 4 + j * 16;
        short4 vh, vl;
        float f0 = tile[c0 + 0][px], f1 = tile[c0 + 1][px];
        float f2 = tile[c0 + 2][px], f3 = tile[c0 + 3][px];
        vh.x = f2bf(f0); vh.y = f2bf(f1); vh.z = f2bf(f2); vh.w = f2bf(f3);
        vl.x = f2bf(f0 - bf2f(vh.x));
        vl.y = f2bf(f1 - bf2f(vh.y));
        vl.z = f2bf(f2 - bf2f(vh.z));
        vl.w = f2bf(f3 - bf2f(vh.w));
        *(short4*)(dsth + c0) = vh;
        *(short4*)(dstl + c0) = vl;
    }
}

// ---------------------------------------------------------------------------
// Kernel A2: wt (O,C,3,3) f32 -> wb[k][o][c] bf16
// ---------------------------------------------------------------------------
__global__ void prep_w(const float* __restrict__ wt, short* __restrict__ wb) {
    int idx = blockIdx.x * 256 + threadIdx.x;     // K*O*C = 147456
    if (idx >= Kk * On * Cc) return;
    int c = idx & 127;
    int o = (idx >> 7) & 127;
    int k = idx >> 14;
    wb[idx] = f2bf(wt[(o * Cc + c) * 9 + k]);
}

// ---------------------------------------------------------------------------
// Kernel A3: offset/mask weights -> wofm_{hi,lo}[k][ch32][c].
// ---------------------------------------------------------------------------
__global__ void prep_wofm(const float* __restrict__ w_off,
                          const float* __restrict__ w_mask,
                          short* __restrict__ wh, short* __restrict__ wl) {
    int idx = blockIdx.x * 256 + threadIdx.x;     // 9*32*128 = 36864
    if (idx >= Kk * 32 * Cc) return;
    int c = idx & 127;
    int ch = (idx >> 7) & 31;
    int k = idx >> 12;
    float v = 0.f;
    if (ch < 18)      v = w_off[(ch * Cc + c) * 9 + k];
    else if (ch < 27) v = w_mask[((ch - 18) * Cc + c) * 9 + k];
    short hi = f2bf(v);
    wh[idx] = hi;
    wl[idx] = f2bf(v - bf2f(hi));
}

// ---------------------------------------------------------------------------
// Kernel C (FUSED): offset/mask conv (phase 1) + main deformable conv
// (phase 2) in one dispatch.
//
// Phase 1 (per wave, NO barriers): r8-proven hi/lo MFMA offmask for the
// wave's own 16 pixels. A per-lane from xT/xLo with clamp + zero-select
// (== r8's zero-filled halo values), B reg-double-buffered from wofm.
// Bias+sigmoid applied, D written to om_lds — wave-private handoff:
// every om value a wave consumes in phase 2, it produced itself.
//
// Phase 2: r11 k-loop verbatim; SETUP reads dy/dx/mk from om_lds.
// Numerics of both phases byte-identical to round 11.
// ---------------------------------------------------------------------------
__global__ __launch_bounds__(256) void dconv_fused(
    const short* __restrict__ xT,    // [b][hw][c] bf16 hi
    const short* __restrict__ xLo,   // [b][hw][c] bf16 lo
    const short* __restrict__ wb,    // [k][o][c] bf16   (main weights)
    const short* __restrict__ wh,    // [k][ch32][c] bf16 hi (offmask w)
    const short* __restrict__ wl,    // [k][ch32][c] bf16 lo
    const float* __restrict__ b_off, const float* __restrict__ b_mask,
    const float* __restrict__ bias,
    float* __restrict__ out)
{
    __shared__ short w_lds[2][128 * 128];   // 64 KB, byte ^= (o&15)<<4
    __shared__ float om_lds[32 * OMP];      // 8.8 KB: [ch][px] f32

    // XCD-chunked swizzle: 1600 blocks = 8 XCDs x 200 contiguous (b,tile).
    const int g = blockIdx.x;
    const int orig = (g & 7) * 200 + (g >> 3);
    const int b = orig / 400;
    const int p0 = (orig % 400) * 64;

    const int t = threadIdx.x;
    const int lane = t & 63;
    const int wid = t >> 6;
    const int pm = wid * 16;

    const int i16 = lane & 15;
    const int myPx = pm + i16;           // block-local pixel this lane owns
    const int p = p0 + myPx;             // global pixel
    const int h = p / Ww, w = p % Ww;
    const int kb8 = (lane >> 4) * 8;     // channel slice base

    const short* xh_b = xT  + (size_t)b * HW * Cc;
    const short* xl_b = xLo + (size_t)b * HW * Cc;
    const short* xbase = xh_b + kb8;

    const s16x8 vz = {0, 0, 0, 0, 0, 0, 0, 0};

    // ======================= PHASE 1: offset/mask conv =======================
    {
        f32x4 acc2[2];
        acc2[0] = (f32x4){0.f, 0.f, 0.f, 0.f};
        acc2[1] = (f32x4){0.f, 0.f, 0.f, 0.f};

        s16x8 bhf[2][2][4], blf[2][2][4];   // B dbuf (r8 pattern)
#pragma unroll
        for (int t2 = 0; t2 < 2; ++t2) {
            const short* bp = wh + ((size_t)(t2 * 16 + i16)) * Cc + kb8;
            const short* lp = wl + ((size_t)(t2 * 16 + i16)) * Cc + kb8;
#pragma unroll
            for (int kk = 0; kk < 4; ++kk) {
                bhf[0][t2][kk] = *(const s16x8*)(bp + kk * 32);
                blf[0][t2][kk] = *(const s16x8*)(lp + kk * 32);
            }
        }

#pragma unroll
        for (int k = 0; k < Kk; ++k) {
            const int cur = k & 1, nxt = cur ^ 1;
            if (k < Kk - 1) {
                const int kn = k + 1;
#pragma unroll
                for (int t2 = 0; t2 < 2; ++t2) {
                    const short* bp = wh + ((size_t)(kn * 32 + t2 * 16 + i16)) * Cc + kb8;
                    const short* lp = wl + ((size_t)(kn * 32 + t2 * 16 + i16)) * Cc + kb8;
#pragma unroll
                    for (int kk = 0; kk < 4; ++kk) {
                        bhf[nxt][t2][kk] = *(const s16x8*)(bp + kk * 32);
                        blf[nxt][t2][kk] = *(const s16x8*)(lp + kk * 32);
                    }
                }
            }
            // A: this lane's pixel, tap (ky,kx), clamp + zero-select
            const int r  = h + (k / 3) - 1;
            const int cl = w + (k % 3) - 1;
            const bool ok = ((unsigned)r < (unsigned)Hh) && ((unsigned)cl < (unsigned)Ww);
            const int rc = min(max(r, 0), Hh - 1) * Ww + min(max(cl, 0), Ww - 1);
            const short* pa  = xh_b + (size_t)rc * Cc + kb8;
            const short* pl2 = xl_b + (size_t)rc * Cc + kb8;
            s16x8 ah[4], al[4];
#pragma unroll
            for (int kk = 0; kk < 4; ++kk) {
                ah[kk] = *(const s16x8*)(pa + kk * 32);
                al[kk] = *(const s16x8*)(pl2 + kk * 32);
            }
            if (!ok) {
#pragma unroll
                for (int kk = 0; kk < 4; ++kk) { ah[kk] = vz; al[kk] = vz; }
            }
#pragma unroll
            for (int t2 = 0; t2 < 2; ++t2) {
#pragma unroll
                for (int kk = 0; kk < 4; ++kk) {
                    acc2[t2] = __builtin_amdgcn_mfma_f32_16x16x32_bf16(ah[kk], bhf[cur][t2][kk], acc2[t2], 0, 0, 0);
                    acc2[t2] = __builtin_amdgcn_mfma_f32_16x16x32_bf16(al[kk], bhf[cur][t2][kk], acc2[t2], 0, 0, 0);
                    acc2[t2] = __builtin_amdgcn_mfma_f32_16x16x32_bf16(ah[kk], blf[cur][t2][kk], acc2[t2], 0, 0, 0);
                }
            }
        }

        // epilogue -> om_lds (D: col=lane&15 -> ch, row=(lane>>4)*4+reg -> px)
#pragma unroll
        for (int t2 = 0; t2 < 2; ++t2) {
            int ch = t2 * 16 + i16;
#pragma unroll
            for (int reg = 0; reg < 4; ++reg) {
                int pxl = pm + (lane >> 4) * 4 + reg;
                float v = acc2[t2][reg];
                if (ch < 18)       v += b_off[ch];
                else if (ch < 27)  v = 1.f / (1.f + expf(-(v + b_mask[ch - 18])));
                om_lds[ch * OMP + pxl] = v;
            }
        }
    }
    // No barrier: phase 2 reads only om values this wave just wrote.

    // ======================= PHASE 2: main deform conv =======================
    f32x4 acc[8];
#pragma unroll
    for (int i = 0; i < 8; ++i) acc[i] = (f32x4){0.f, 0.f, 0.f, 0.f};

    float wgbuf[2][4];
    int   idxc[4];
    s16x8 G[2][16];
    int4  Wr[8];

#define SETUP(kq, wbuf)                                                        \
    {                                                                          \
        float dyv = om_lds[(2 * (kq)) * OMP + myPx];                           \
        float dxv = om_lds[(2 * (kq) + 1) * OMP + myPx];                       \
        float mv  = om_lds[(18 + (kq)) * OMP + myPx];                          \
        float py  = (float)(h + ((kq) / 3) - 1) + dyv;                         \
        float pxf = (float)(w + ((kq) % 3) - 1) + dxv;                         \
        float y0f = floorf(py), x0f = floorf(pxf);                             \
        float ly = py - y0f, lx = pxf - x0f;                                   \
        int y0 = (int)y0f, x0 = (int)x0f;                                      \
        _Pragma("unroll")                                                      \
        for (int cr = 0; cr < 4; ++cr) {                                       \
            int iy = y0 + (cr >> 1), ix = x0 + (cr & 1);                       \
            bool ok = ((unsigned)iy < (unsigned)Hh) && ((unsigned)ix < (unsigned)Ww); \
            float wy = (cr >> 1) ? ly : (1.f - ly);                            \
            float wx = (cr & 1) ? lx : (1.f - lx);                             \
            int cy = min(max(iy, 0), Hh - 1);                                  \
            int cx = min(max(ix, 0), Ww - 1);                                  \
            idxc[cr] = cy * Ww + cx;                                           \
            wgbuf[wbuf][cr] = ok ? (wy * wx * mv) : 0.f;                       \
        }                                                                      \
    }

#define ISSUEG(gbuf)                                                           \
    {                                                                          \
        _Pragma("unroll")                                                      \
        for (int cr = 0; cr < 4; ++cr) {                                       \
            const short* src = xbase + (size_t)idxc[cr] * Cc;                  \
            _Pragma("unroll")                                                  \
            for (int kk = 0; kk < 4; ++kk)                                     \
                G[gbuf][cr * 4 + kk] = *(const s16x8*)(src + kk * 32);         \
        }                                                                      \
    }

#define LOADW(kq)                                                              \
    {                                                                          \
        const int4* src = (const int4*)(wb + (size_t)(kq) * 128 * 128);        \
        _Pragma("unroll")                                                      \
        for (int i2 = 0; i2 < 8; ++i2) Wr[i2] = src[i2 * 256 + t];             \
    }

#define WRITEW(bufIdx)                                                         \
    {                                                                          \
        _Pragma("unroll")                                                      \
        for (int i2 = 0; i2 < 8; ++i2) {                                       \
            int ci = i2 * 256 + t;                                             \
            int o = ci >> 4;                                                   \
            int byte = (ci << 4) ^ ((o & 15) << 4);                            \
            *(int4*)((char*)w_lds[bufIdx] + byte) = Wr[i2];                    \
        }                                                                      \
    }

    // ---- prologue ----
    LOADW(0);
    SETUP(0, 0);
    ISSUEG(0);
    WRITEW(0);
    __syncthreads();

#pragma unroll
    for (int k = 0; k < Kk; ++k) {
        if (k < Kk - 1) LOADW(k + 1);
        if (k < Kk - 1) {
            SETUP(k + 1, (k + 1) & 1);
            ISSUEG((k + 1) & 1);
        }

        // ---- blend(k): consumes G[k&1], wgbuf[k&1] ----
        s16x8 afr[4];
#pragma unroll
        for (int kk = 0; kk < 4; ++kk) {
#pragma unroll
            for (int j = 0; j < 8; ++j) {
                float sv = wgbuf[k & 1][0] * bf2f(G[k & 1][0 * 4 + kk][j])
                         + wgbuf[k & 1][1] * bf2f(G[k & 1][1 * 4 + kk][j])
                         + wgbuf[k & 1][2] * bf2f(G[k & 1][2 * 4 + kk][j])
                         + wgbuf[k & 1][3] * bf2f(G[k & 1][3 * 4 + kk][j]);
                afr[kk][j] = f2bf(sv);
            }
        }

        // ---- MFMA(k): A in regs, B from w_lds[k&1] ----
        {
            const int orow = lane & 15;
#pragma unroll
            for (int ot = 0; ot < 8; ++ot) {
                int o = ot * 16 + orow;
#pragma unroll
                for (int kk = 0; kk < 4; ++kk) {
                    int byte = (o * 256 + (kk * 32 + kb8) * 2) ^ ((o & 15) << 4);
                    s16x8 bfr = *(const s16x8*)((char*)w_lds[k & 1] + byte);
                    acc[ot] = __builtin_amdgcn_mfma_f32_16x16x32_bf16(afr[kk], bfr, acc[ot], 0, 0, 0);
                }
            }
        }

        if (k < Kk - 1) WRITEW((k + 1) & 1);
        __syncthreads();
    }

#undef SETUP
#undef ISSUEG
#undef LOADW
#undef WRITEW

    // ---- epilogue: D col=lane&15 (o), row=(lane>>4)*4+reg (px) ----
#pragma unroll
    for (int ot = 0; ot < 8; ++ot) {
        int o = ot * 16 + (lane & 15);
        float bo = bias[o];
        float4 r;
        r.x = acc[ot][0] + bo;
        r.y = acc[ot][1] + bo;
        r.z = acc[ot][2] + bo;
        r.w = acc[ot][3] + bo;
        *(float4*)(out + ((size_t)(b * On + o)) * HW + p0 + pm + (lane >> 4) * 4) = r;
    }
}

// ---------------------------------------------------------------------------
extern "C" void kernel_launch(void* const* d_in, const int* in_sizes, int n_in,
                              void* d_out, int out_size, void* d_ws, size_t ws_size,
                              hipStream_t stream) {
    const float* x      = (const float*)d_in[0];
    const float* w_off  = (const float*)d_in[1];
    const float* b_off  = (const float*)d_in[2];
    const float* w_mask = (const float*)d_in[3];
    const float* b_mask = (const float*)d_in[4];
    const float* wt     = (const float*)d_in[5];
    const float* bias   = (const float*)d_in[6];
    float* out = (float*)d_out;

    short* xT  = (short*)d_ws;                      // B*HW*C bf16 hi
    short* xLo = xT + (size_t)Bn * HW * Cc;         // B*HW*C bf16 lo
    short* wb  = xLo + (size_t)Bn * HW * Cc;        // K*O*C bf16
    short* wofm_h = wb + Kk * On * Cc;              // 9*32*128 bf16
    short* wofm_l = wofm_h + Kk * 32 * Cc;          // 9*32*128 bf16

    to_nhwc<<<dim3(HW / 64, Bn), 256, 0, stream>>>(x, xT, xLo);
    prep_w<<<(Kk * On * Cc + 255) / 256, 256, 0, stream>>>(wt, wb);
    prep_wofm<<<(Kk * 32 * Cc + 255) / 256, 256, 0, stream>>>(w_off, w_mask, wofm_h, wofm_l);
    dconv_fused<<<1600, 256, 0, stream>>>(
        xT, xLo, wb, wofm_h, wofm_l, b_off, b_mask, bias, out);
}

// Round 13
// 302.227 us; speedup vs baseline: 1.0826x; 1.0826x over previous
//
#include <hip/hip_runtime.h>
#include <math.h>

constexpr int Bn = 4, Cc = 128, On = 128, Hh = 160, Ww = 160, Kk = 9;
constexpr int HW = Hh * Ww;          // 25600

typedef __attribute__((ext_vector_type(8))) short s16x8;
typedef __attribute__((ext_vector_type(4))) float f32x4;

__device__ inline float bf2f(short s) {
    union { float f; unsigned u; } v;
    v.u = ((unsigned)(unsigned short)s) << 16;
    return v.f;
}
__device__ inline short f2bf(float f) {
    union { float f; unsigned u; } v;
    v.f = f;
    unsigned r = v.u + 0x7fffu + ((v.u >> 16) & 1u);   // RNE
    return (short)(r >> 16);
}

// ---------------------------------------------------------------------------
// Kernel A1: x (NCHW f32) -> xT (NHWC bf16 hi) + xLo (NHWC bf16 lo).
// ---------------------------------------------------------------------------
__global__ __launch_bounds__(256) void to_nhwc(const float* __restrict__ x,
                                               short* __restrict__ xT,
                                               short* __restrict__ xLo) {
    __shared__ float tile[128][65];
    const int t = threadIdx.x;
    const int p0 = blockIdx.x * 64;
    const int b = blockIdx.y;
#pragma unroll
    for (int i = 0; i < 32; ++i) {
        int c = i * 4 + (t >> 6);
        tile[c][t & 63] = x[((size_t)b * Cc + c) * HW + p0 + (t & 63)];
    }
    __syncthreads();
    const int px = t >> 2, cq = t & 3;
    short* dsth = xT  + ((size_t)(b * HW) + p0 + px) * Cc;
    short* dstl = xLo + ((size_t)(b * HW) + p0 + px) * Cc;
#pragma unroll
    for (int j = 0; j < 8; ++j) {
        int c0 = cq * 4 + j * 16;
        short4 vh, vl;
        float f0 = tile[c0 + 0][px], f1 = tile[c0 + 1][px];
        float f2 = tile[c0 + 2][px], f3 = tile[c0 + 3][px];
        vh.x = f2bf(f0); vh.y = f2bf(f1); vh.z = f2bf(f2); vh.w = f2bf(f3);
        vl.x = f2bf(f0 - bf2f(vh.x));
        vl.y = f2bf(f1 - bf2f(vh.y));
        vl.z = f2bf(f2 - bf2f(vh.z));
        vl.w = f2bf(f3 - bf2f(vh.w));
        *(short4*)(dsth + c0) = vh;
        *(short4*)(dstl + c0) = vl;
    }
}

// ---------------------------------------------------------------------------
// Kernel A2: wt (O,C,3,3) f32 -> wb[k][o][c] bf16
// ---------------------------------------------------------------------------
__global__ void prep_w(const float* __restrict__ wt, short* __restrict__ wb) {
    int idx = blockIdx.x * 256 + threadIdx.x;     // K*O*C = 147456
    if (idx >= Kk * On * Cc) return;
    int c = idx & 127;
    int o = (idx >> 7) & 127;
    int k = idx >> 14;
    wb[idx] = f2bf(wt[(o * Cc + c) * 9 + k]);
}

// ---------------------------------------------------------------------------
// Kernel A3: offset/mask weights -> wofm_{hi,lo}[k][ch32][c].
// ---------------------------------------------------------------------------
__global__ void prep_wofm(const float* __restrict__ w_off,
                          const float* __restrict__ w_mask,
                          short* __restrict__ wh, short* __restrict__ wl) {
    int idx = blockIdx.x * 256 + threadIdx.x;     // 9*32*128 = 36864
    if (idx >= Kk * 32 * Cc) return;
    int c = idx & 127;
    int ch = (idx >> 7) & 31;
    int k = idx >> 12;
    float v = 0.f;
    if (ch < 18)      v = w_off[(ch * Cc + c) * 9 + k];
    else if (ch < 27) v = w_mask[((ch - 18) * Cc + c) * 9 + k];
    short hi = f2bf(v);
    wh[idx] = hi;
    wl[idx] = f2bf(v - bf2f(hi));
}

// ---------------------------------------------------------------------------
// Kernel B: offset/mask conv via MFMA, hi/lo split (unchanged from r8/r11).
// ---------------------------------------------------------------------------
__global__ __launch_bounds__(256) void offmask_mfma(
    const short* __restrict__ xT, const short* __restrict__ xLo,
    const short* __restrict__ wh, const short* __restrict__ wl,
    const float* __restrict__ b_off, const float* __restrict__ b_mask,
    float* __restrict__ dy_o, float* __restrict__ dx_o, float* __restrict__ mk_o)
{
    __shared__ short a_hi[6][2304];
    __shared__ short a_lo[6][2304];

    const int g = blockIdx.x;
    const int orig = (g & 7) * 200 + (g >> 3);
    const int b  = orig / 400;
    const int rem = orig % 400;
    const int h0 = (rem / 10) * 4;
    const int w0 = (rem % 10) * 16;

    const int t = threadIdx.x;

    const short* xh_b = xT  + (size_t)b * HW * Cc;
    const short* xl_b = xLo + (size_t)b * HW * Cc;
#pragma unroll
    for (int j = 0; j < 14; ++j) {
        int ci = j * 256 + t;
        if (ci < 3456) {
            int slot = ci / 576;
            int rem2 = ci % 576;
            int isLo = rem2 >= 288;
            int cj   = isLo ? rem2 - 288 : rem2;
            int pxl  = cj >> 4;
            int ck   = cj & 15;
            int r   = h0 - 1 + slot;
            int col = w0 - 1 + pxl;
            int4 v = make_int4(0, 0, 0, 0);
            if ((unsigned)r < (unsigned)Hh && (unsigned)col < (unsigned)Ww) {
                const short* src = (isLo ? xl_b : xh_b) +
                                   ((size_t)(r * Ww + col)) * Cc + ck * 8;
                v = *(const int4*)src;
            }
            int byte = (pxl * 256 + ck * 16) ^ ((pxl & 7) << 4);
            *(int4*)((char*)(isLo ? a_lo[slot] : a_hi[slot]) + byte) = v;
        }
    }
    __syncthreads();

    const int lane = t & 63, wid = t >> 6;
    const int i  = lane & 15;
    const int kb = (lane >> 4) * 8;

    f32x4 acc[2];
    acc[0] = (f32x4){0.f, 0.f, 0.f, 0.f};
    acc[1] = (f32x4){0.f, 0.f, 0.f, 0.f};

    s16x8 bh[2][2][4], bl[2][2][4];

#pragma unroll
    for (int tile = 0; tile < 2; ++tile) {
        const short* bp = wh + ((size_t)(tile * 16 + i)) * Cc + kb;
        const short* lp = wl + ((size_t)(tile * 16 + i)) * Cc + kb;
#pragma unroll
        for (int kk = 0; kk < 4; ++kk) {
            bh[0][tile][kk] = *(const s16x8*)(bp + kk * 32);
            bl[0][tile][kk] = *(const s16x8*)(lp + kk * 32);
        }
    }

#pragma unroll
    for (int k = 0; k < Kk; ++k) {
        const int cur = k & 1, nxt = cur ^ 1;
        if (k < Kk - 1) {
            const int kn = k + 1;
#pragma unroll
            for (int tile = 0; tile < 2; ++tile) {
                const short* bp = wh + ((size_t)(kn * 32 + tile * 16 + i)) * Cc + kb;
                const short* lp = wl + ((size_t)(kn * 32 + tile * 16 + i)) * Cc + kb;
#pragma unroll
                for (int kk = 0; kk < 4; ++kk) {
                    bh[nxt][tile][kk] = *(const s16x8*)(bp + kk * 32);
                    bl[nxt][tile][kk] = *(const s16x8*)(lp + kk * 32);
                }
            }
        }
        const int ky = k / 3, kxi = k % 3;
        const int slot = wid + ky;
        const int pxl = i + kxi;
        s16x8 ah[4], al[4];
#pragma unroll
        for (int kk = 0; kk < 4; ++kk) {
            int byte = (pxl * 256 + (kk * 32 + kb) * 2) ^ ((pxl & 7) << 4);
            ah[kk] = *(const s16x8*)((char*)a_hi[slot] + byte);
            al[kk] = *(const s16x8*)((char*)a_lo[slot] + byte);
        }
#pragma unroll
        for (int tile = 0; tile < 2; ++tile) {
#pragma unroll
            for (int kk = 0; kk < 4; ++kk) {
                acc[tile] = __builtin_amdgcn_mfma_f32_16x16x32_bf16(ah[kk], bh[cur][tile][kk], acc[tile], 0, 0, 0);
                acc[tile] = __builtin_amdgcn_mfma_f32_16x16x32_bf16(al[kk], bh[cur][tile][kk], acc[tile], 0, 0, 0);
                acc[tile] = __builtin_amdgcn_mfma_f32_16x16x32_bf16(ah[kk], bl[cur][tile][kk], acc[tile], 0, 0, 0);
            }
        }
    }

    const int hr = h0 + wid;
#pragma unroll
    for (int tile = 0; tile < 2; ++tile) {
        int ch = tile * 16 + i;
#pragma unroll
        for (int reg = 0; reg < 4; ++reg) {
            int pxo = (lane >> 4) * 4 + reg;
            int p = hr * Ww + w0 + pxo;
            float v = acc[tile][reg];
            if (ch < 18) {
                int k = ch >> 1;
                v += b_off[ch];
                if (ch & 1) dx_o[(size_t)(b * 9 + k) * HW + p] = v;
                else        dy_o[(size_t)(b * 9 + k) * HW + p] = v;
            } else if (ch < 27) {
                int k = ch - 18;
                v += b_mask[k];
                mk_o[(size_t)(b * 9 + k) * HW + p] = 1.f / (1.f + expf(-v));
            }
        }
    }
}

// ---------------------------------------------------------------------------
// Kernel C: main deformable conv — r11 pipeline, ONE edit: 2-D pixel tiles.
// Block = 4 rows x 16 cols (wave wid owns row h0+wid, cols w0..w0+15),
// same decomposition as offmask_mfma. Gather window shrinks ~166KB->~103KB
// with high cross-k/cross-wave row reuse -> more L1 hits, fewer L2 lines.
// Per-pixel numerics, MFMA layout, pipeline: byte-identical to r11.
// ---------------------------------------------------------------------------
__global__ __launch_bounds__(256) void dconv_main(
    const short* __restrict__ xT,    // [b][hw][c] bf16
    const short* __restrict__ wb,    // [k][o][c] bf16
    const float* __restrict__ bias,
    const float* __restrict__ dy_i, const float* __restrict__ dx_i,
    const float* __restrict__ mk_i,
    float* __restrict__ out)
{
    __shared__ short w_lds[2][128 * 128];   // 2 x 32 KB, byte ^= (o&15)<<4

    // XCD-chunked swizzle: 1600 blocks = 8 XCDs x 200 contiguous (b,h0,w0).
    const int g = blockIdx.x;
    const int orig = (g & 7) * 200 + (g >> 3);
    const int b = orig / 400;
    const int rem = orig % 400;
    const int h0 = (rem / 10) * 4;       // 40 bands of 4 rows
    const int w0 = (rem % 10) * 16;      // 10 bands of 16 cols

    const int t = threadIdx.x;
    const int lane = t & 63;
    const int wid = t >> 6;

    const int i16 = lane & 15;
    const int h = h0 + wid;              // wave-uniform row
    const int w = w0 + i16;              // this lane's column
    const int p = h * Ww + w;            // this lane's global pixel
    const int kb8 = (lane >> 4) * 8;     // channel slice base

    const short* xbase = xT + (size_t)b * HW * Cc + kb8;

    f32x4 acc[8];
#pragma unroll
    for (int i = 0; i < 8; ++i) acc[i] = (f32x4){0.f, 0.f, 0.f, 0.f};

    float wgbuf[2][4];
    int   idxc[4];
    s16x8 G[2][16];
    float omv[2][3];
    int4  Wr[8];

#define SETUP(kq, wbuf, dyv, dxv, mv)                                          \
    {                                                                          \
        float py  = (float)(h + ((kq) / 3) - 1) + (dyv);                       \
        float pxf = (float)(w + ((kq) % 3) - 1) + (dxv);                       \
        float y0f = floorf(py), x0f = floorf(pxf);                             \
        float ly = py - y0f, lx = pxf - x0f;                                   \
        int y0 = (int)y0f, x0 = (int)x0f;                                      \
        _Pragma("unroll")                                                      \
        for (int cr = 0; cr < 4; ++cr) {                                       \
            int iy = y0 + (cr >> 1), ix = x0 + (cr & 1);                       \
            bool ok = ((unsigned)iy < (unsigned)Hh) && ((unsigned)ix < (unsigned)Ww); \
            float wy = (cr >> 1) ? ly : (1.f - ly);                            \
            float wx = (cr & 1) ? lx : (1.f - lx);                             \
            int cy = min(max(iy, 0), Hh - 1);                                  \
            int cx = min(max(ix, 0), Ww - 1);                                  \
            idxc[cr] = cy * Ww + cx;                                           \
            wgbuf[wbuf][cr] = ok ? (wy * wx * (mv)) : 0.f;                     \
        }                                                                      \
    }

#define ISSUEG(gbuf)                                                           \
    {                                                                          \
        _Pragma("unroll")                                                      \
        for (int cr = 0; cr < 4; ++cr) {                                       \
            const short* src = xbase + (size_t)idxc[cr] * Cc;                  \
            _Pragma("unroll")                                                  \
            for (int kk = 0; kk < 4; ++kk)                                     \
                G[gbuf][cr * 4 + kk] = *(const s16x8*)(src + kk * 32);         \
        }                                                                      \
    }

#define LOADOM(kq, obuf)                                                       \
    {                                                                          \
        size_t ob = (size_t)(b * 9 + (kq)) * HW + p;                           \
        omv[obuf][0] = dy_i[ob]; omv[obuf][1] = dx_i[ob]; omv[obuf][2] = mk_i[ob]; \
    }

#define LOADW(kq)                                                              \
    {                                                                          \
        const int4* src = (const int4*)(wb + (size_t)(kq) * 128 * 128);        \
        _Pragma("unroll")                                                      \
        for (int i2 = 0; i2 < 8; ++i2) Wr[i2] = src[i2 * 256 + t];             \
    }

#define WRITEW(bufIdx)                                                         \
    {                                                                          \
        _Pragma("unroll")                                                      \
        for (int i2 = 0; i2 < 8; ++i2) {                                       \
            int ci = i2 * 256 + t;                                             \
            int o = ci >> 4;                                                   \
            int byte = (ci << 4) ^ ((o & 15) << 4);                            \
            *(int4*)((char*)w_lds[bufIdx] + byte) = Wr[i2];                    \
        }                                                                      \
    }

    // ---- prologue ----
    LOADW(0);
    LOADOM(0, 0);
    LOADOM(1, 1);
    SETUP(0, 0, omv[0][0], omv[0][1], omv[0][2]);
    ISSUEG(0);
    WRITEW(0);
    __syncthreads();

#pragma unroll
    for (int k = 0; k < Kk; ++k) {
        if (k < Kk - 1) LOADW(k + 1);
        if (k < Kk - 2) LOADOM(k + 2, k & 1);
        if (k < Kk - 1) {
            SETUP(k + 1, (k + 1) & 1,
                  omv[(k + 1) & 1][0], omv[(k + 1) & 1][1], omv[(k + 1) & 1][2]);
            ISSUEG((k + 1) & 1);
        }

        // ---- blend(k): consumes G[k&1], wgbuf[k&1] ----
        s16x8 afr[4];
#pragma unroll
        for (int kk = 0; kk < 4; ++kk) {
#pragma unroll
            for (int j = 0; j < 8; ++j) {
                float sv = wgbuf[k & 1][0] * bf2f(G[k & 1][0 * 4 + kk][j])
                         + wgbuf[k & 1][1] * bf2f(G[k & 1][1 * 4 + kk][j])
                         + wgbuf[k & 1][2] * bf2f(G[k & 1][2 * 4 + kk][j])
                         + wgbuf[k & 1][3] * bf2f(G[k & 1][3 * 4 + kk][j]);
                afr[kk][j] = f2bf(sv);
            }
        }

        // ---- MFMA(k): A in regs, B from w_lds[k&1] ----
        {
            const int orow = lane & 15;
#pragma unroll
            for (int ot = 0; ot < 8; ++ot) {
                int o = ot * 16 + orow;
#pragma unroll
                for (int kk = 0; kk < 4; ++kk) {
                    int byte = (o * 256 + (kk * 32 + kb8) * 2) ^ ((o & 15) << 4);
                    s16x8 bfr = *(const s16x8*)((char*)w_lds[k & 1] + byte);
                    acc[ot] = __builtin_amdgcn_mfma_f32_16x16x32_bf16(afr[kk], bfr, acc[ot], 0, 0, 0);
                }
            }
        }

        if (k < Kk - 1) WRITEW((k + 1) & 1);
        __syncthreads();
    }

#undef SETUP
#undef ISSUEG
#undef LOADOM
#undef LOADW
#undef WRITEW

    // ---- epilogue: D col=lane&15 (o), row=(lane>>4)*4+reg (px in wave row) ----
#pragma unroll
    for (int ot = 0; ot < 8; ++ot) {
        int o = ot * 16 + (lane & 15);
        float bo = bias[o];
        float4 r;
        r.x = acc[ot][0] + bo;
        r.y = acc[ot][1] + bo;
        r.z = acc[ot][2] + bo;
        r.w = acc[ot][3] + bo;
        *(float4*)(out + ((size_t)(b * On + o)) * HW + h * Ww + w0 + (lane >> 4) * 4) = r;
    }
}

// ---------------------------------------------------------------------------
extern "C" void kernel_launch(void* const* d_in, const int* in_sizes, int n_in,
                              void* d_out, int out_size, void* d_ws, size_t ws_size,
                              hipStream_t stream) {
    const float* x      = (const float*)d_in[0];
    const float* w_off  = (const float*)d_in[1];
    const float* b_off  = (const float*)d_in[2];
    const float* w_mask = (const float*)d_in[3];
    const float* b_mask = (const float*)d_in[4];
    const float* wt     = (const float*)d_in[5];
    const float* bias   = (const float*)d_in[6];
    float* out = (float*)d_out;

    short* xT  = (short*)d_ws;                      // B*HW*C bf16 hi
    short* xLo = xT + (size_t)Bn * HW * Cc;         // B*HW*C bf16 lo
    short* wb  = xLo + (size_t)Bn * HW * Cc;        // K*O*C bf16
    short* wofm_h = wb + Kk * On * Cc;
    short* wofm_l = wofm_h + Kk * 32 * Cc;
    float* dy = (float*)(wofm_l + Kk * 32 * Cc);
    float* dx = dy + (size_t)Bn * 9 * HW;
    float* mk = dx + (size_t)Bn * 9 * HW;

    to_nhwc<<<dim3(HW / 64, Bn), 256, 0, stream>>>(x, xT, xLo);
    prep_w<<<(Kk * On * Cc + 255) / 256, 256, 0, stream>>>(wt, wb);
    prep_wofm<<<(Kk * 32 * Cc + 255) / 256, 256, 0, stream>>>(w_off, w_mask, wofm_h, wofm_l);
    offmask_mfma<<<1600, 256, 0, stream>>>(
        xT, xLo, wofm_h, wofm_l, b_off, b_mask, dy, dx, mk);
    dconv_main<<<1600, 256, 0, stream>>>(
        xT, wb, bias, dy, dx, mk, out);
}